// Round 5
// baseline (153.289 us; speedup 1.0000x reference)
//
#include <hip/hip_runtime.h>
#include <hip/hip_bf16.h>

// Polyphase 2x upsample, depthwise 12-tap, reflect pad, fp32.
// out[b,c,oh,ow] = 4 * sum_{m,n=0..5} x[b,c,reflect(q_y+2+py+m-5),reflect(q_x+2+px+n-5)]
//                       * filt[11-py-2m][11-px-2n],  oh=2*q_y+py, ow=2*q_x+px

__global__ __launch_bounds__(256) void upsample2d_kernel(
    const float* __restrict__ x, const float* __restrict__ filt,
    float* __restrict__ out)
{
    __shared__ float s_in[38 * 40];     // input tile, stride 40 (even -> b64 aligned reads)
    __shared__ float s_f[4][6][6];      // phase-major filter [py*2+px][m][n], pre-scaled by 4

    const int tx = threadIdx.x, ty = threadIdx.y;
    const int tid = ty * 16 + tx;
    const int bc  = blockIdx.z;               // fused (batch, channel), 4*64 = 256
    const int boy = blockIdx.y, box = blockIdx.x;
    const int Q0y = boy * 32, Q0x = box * 32; // block's first input-quad index

    // --- stage filter, rearranged phase-major, scaled by RATIO^2 = 4 ---
    if (tid < 144) {
        int n = tid % 6, m = (tid / 6) % 6, ph = tid / 36;
        int py = ph >> 1, px = ph & 1;
        int jy = 11 - py - 2 * m, jx = 11 - px - 2 * n;
        s_f[ph][m][n] = 4.0f * filt[jy * 12 + jx];
    }

    // --- stage 38x38 input tile with reflect mapping ---
    const float* xc = x + (size_t)bc * 256 * 256;
    for (int idx = tid; idx < 38 * 38; idx += 256) {
        int R = idx / 38, Cc = idx - R * 38;
        int gy = Q0y + R - 3;             // x-row for tile row R (xp index Q0y+2+R, minus PAD=5)
        int gx = Q0x + Cc - 3;
        gy = gy < 0 ? -gy : (gy > 255 ? 510 - gy : gy);
        gx = gx < 0 ? -gx : (gx > 255 ? 510 - gx : gx);
        s_in[R * 40 + Cc] = xc[gy * 256 + gx];
    }
    __syncthreads();

    // --- pull thread's 8x8 input window into registers ---
    float xr[8][8];
    #pragma unroll
    for (int r = 0; r < 8; ++r) {
        #pragma unroll
        for (int c = 0; c < 8; ++c)
            xr[r][c] = s_in[(2 * ty + r) * 40 + (2 * tx + c)];
    }

    // --- 576 FMAs, all indices compile-time after unroll ---
    float acc[4][4] = {};   // [oy 0..3][ox 0..3]
    #pragma unroll
    for (int py = 0; py < 2; ++py)
    #pragma unroll
    for (int px = 0; px < 2; ++px) {
        #pragma unroll
        for (int m = 0; m < 6; ++m)
        #pragma unroll
        for (int n = 0; n < 6; ++n) {
            float f = s_f[py * 2 + px][m][n];
            #pragma unroll
            for (int qy = 0; qy < 2; ++qy)
            #pragma unroll
            for (int qx = 0; qx < 2; ++qx)
                acc[2 * qy + py][2 * qx + px] =
                    fmaf(xr[qy + py + m][qx + px + n], f,
                         acc[2 * qy + py][2 * qx + px]);
        }
    }

    // --- coalesced float4 stores: thread writes rows OY0..OY0+3 at col OX ---
    float* oc = out + (size_t)bc * 512 * 512;
    const int OY0 = boy * 64 + 4 * ty;
    const int OX  = box * 64 + 4 * tx;
    #pragma unroll
    for (int oy = 0; oy < 4; ++oy) {
        float4 v = make_float4(acc[oy][0], acc[oy][1], acc[oy][2], acc[oy][3]);
        *reinterpret_cast<float4*>(&oc[(size_t)(OY0 + oy) * 512 + OX]) = v;
    }
}

extern "C" void kernel_launch(void* const* d_in, const int* in_sizes, int n_in,
                              void* d_out, int out_size, void* d_ws, size_t ws_size,
                              hipStream_t stream) {
    const float* x    = (const float*)d_in[0];   // (4,64,256,256) fp32
    const float* filt = (const float*)d_in[1];   // (12,12) fp32
    float* out = (float*)d_out;                  // (4,64,512,512) fp32

    dim3 grid(8, 8, 4 * 64);   // 8x8 tiles of 64x64 over 512x512, per (b,c)
    dim3 block(16, 16, 1);
    upsample2d_kernel<<<grid, block, 0, stream>>>(x, filt, out);
}

// Round 6
// 144.450 us; speedup vs baseline: 1.0612x; 1.0612x over previous
//
#include <hip/hip_runtime.h>
#include <hip/hip_bf16.h>

// Polyphase 2x upsample, depthwise 12-tap, reflect pad, fp32.
// out[b,c,oh,ow] = 4 * sum_{m,n=0..5} x[b,c,reflect(q_y+py+m-3),reflect(q_x+px+n-3)]
//                       * filt[11-py-2m][11-px-2n],  oh=2*q_y+py, ow=2*q_x+px
//
// R5->R6: block now loops over the 4 batch images at fixed (channel, tile):
//  - all staging/window/store addresses are loop-invariant (computed once)
//  - double-buffered LDS, next image's loads issued before compute (T14-style)
//  - one barrier per image instead of per-block setup x4 blocks

#define LDS_STRIDE 40
#define NLOAD 6            // ceil(38*38 / 256)

__global__ __launch_bounds__(256) void upsample2d_kernel(
    const float* __restrict__ x, const float* __restrict__ filt,
    float* __restrict__ out)
{
    __shared__ float s_in[2][38 * LDS_STRIDE];   // 2 x 6080 B double buffer
    __shared__ float s_f[4][6][6];               // phase-major filter, pre-scaled by 4

    const int tx = threadIdx.x, ty = threadIdx.y;
    const int tid = ty * 16 + tx;
    const int c   = blockIdx.z;                  // channel 0..63
    const int boy = blockIdx.y, box = blockIdx.x;
    const int Q0y = boy * 32, Q0x = box * 32;

    if (tid < 144) {
        int n = tid % 6, m = (tid / 6) % 6, ph = tid / 36;
        int py = ph >> 1, px = ph & 1;
        s_f[ph][m][n] = 4.0f * filt[(11 - py - 2 * m) * 12 + (11 - px - 2 * n)];
    }

    // ---- loop-invariant staging addresses (reflect applied once) ----
    int goff[NLOAD];   // word offset within one channel image
    int lw[NLOAD];     // LDS word offset
    #pragma unroll
    for (int k = 0; k < NLOAD; ++k) {
        int idx = tid + k * 256;
        if (idx > 1443) idx = 1443;              // clamp: duplicate same-value write, benign
        int R = idx / 38, C = idx - R * 38;
        int gy = Q0y + R - 3, gx = Q0x + C - 3;
        gy = gy < 0 ? -gy : (gy > 255 ? 510 - gy : gy);
        gx = gx < 0 ? -gx : (gx > 255 ? 510 - gx : gx);
        goff[k] = gy * 256 + gx;
        lw[k]   = R * LDS_STRIDE + C;
    }

    const int xbase = (2 * ty) * LDS_STRIDE + 2 * tx;
    const int OY0 = boy * 64 + 4 * ty;
    const int OX  = box * 64 + 4 * tx;

    // ---- prologue: stage image b=0 into buffer 0 ----
    {
        const float* xc = x + (size_t)c * 65536;
        float g[NLOAD];
        #pragma unroll
        for (int k = 0; k < NLOAD; ++k) g[k] = xc[goff[k]];
        #pragma unroll
        for (int k = 0; k < NLOAD; ++k) s_in[0][lw[k]] = g[k];
    }
    __syncthreads();

    for (int b = 0; b < 4; ++b) {
        const int cur = b & 1;

        // issue next image's loads first — latency hides under compute below
        float g[NLOAD];
        if (b < 3) {
            const float* xn = x + (size_t)(b + 1) * 4194304 + (size_t)c * 65536;
            #pragma unroll
            for (int k = 0; k < NLOAD; ++k) g[k] = xn[goff[k]];
        }

        // window -> registers
        float xr[8][8];
        #pragma unroll
        for (int r = 0; r < 8; ++r) {
            #pragma unroll
            for (int cc = 0; cc < 8; ++cc)
                xr[r][cc] = s_in[cur][xbase + r * LDS_STRIDE + cc];
        }

        // 576 FMAs, all compile-time indices
        float acc[4][4] = {};
        #pragma unroll
        for (int py = 0; py < 2; ++py)
        #pragma unroll
        for (int px = 0; px < 2; ++px) {
            #pragma unroll
            for (int m = 0; m < 6; ++m)
            #pragma unroll
            for (int n = 0; n < 6; ++n) {
                float f = s_f[py * 2 + px][m][n];
                #pragma unroll
                for (int qy = 0; qy < 2; ++qy)
                #pragma unroll
                for (int qx = 0; qx < 2; ++qx)
                    acc[2 * qy + py][2 * qx + px] =
                        fmaf(xr[qy + py + m][qx + px + n], f,
                             acc[2 * qy + py][2 * qx + px]);
            }
        }

        // coalesced float4 stores
        float* oc = out + (size_t)(b * 64 + c) * 262144;
        #pragma unroll
        for (int oy = 0; oy < 4; ++oy) {
            float4 v = make_float4(acc[oy][0], acc[oy][1], acc[oy][2], acc[oy][3]);
            *reinterpret_cast<float4*>(&oc[(size_t)(OY0 + oy) * 512 + OX]) = v;
        }

        // stage next image into the other buffer, then one barrier
        if (b < 3) {
            #pragma unroll
            for (int k = 0; k < NLOAD; ++k) s_in[cur ^ 1][lw[k]] = g[k];
            __syncthreads();
        }
    }
}

extern "C" void kernel_launch(void* const* d_in, const int* in_sizes, int n_in,
                              void* d_out, int out_size, void* d_ws, size_t ws_size,
                              hipStream_t stream) {
    const float* x    = (const float*)d_in[0];   // (4,64,256,256) fp32
    const float* filt = (const float*)d_in[1];   // (12,12) fp32
    float* out = (float*)d_out;                  // (4,64,512,512) fp32

    dim3 grid(8, 8, 64);    // 8x8 tiles of 64x64; z = channel; batch looped in-kernel
    dim3 block(16, 16, 1);
    upsample2d_kernel<<<grid, block, 0, stream>>>(x, filt, out);
}

// Round 7
// 92.033 us; speedup vs baseline: 1.6656x; 1.5695x over previous
//
#include <hip/hip_runtime.h>

// Polyphase 2x upsample, depthwise 12-tap, reflect pad, fp32.
// out[b,c,oh,ow] = 4 * sum_{m,n=0..5} x[b,c,reflect(q_y+py+m-3),reflect(q_x+px+n-3)]
//                       * filt[11-py-2m][11-px-2n],  oh=2*q_y+py, ow=2*q_x+px
//
// R6->R7: barrier-free wave-private staging.
//  - each wave stages its own 14x38 input slab -> NO __syncthreads, stores
//    never drained in-kernel (R6's barrier forced vmcnt(0) incl. stores)
//  - filter read as wave-uniform scalar loads (s_load + SGPR fmac operand):
//    no LDS, no VGPRs, x4 scale folded into the epilogue
//  - no batch loop: 16384 independent blocks, VGPR back under 128 (4 w/SIMD)

#define S 40            // LDS row stride in words (keeps b64 reads bank-optimal)
#define WREG (14 * S)   // per-wave region: 14 rows x 40 words = 560

__global__ __launch_bounds__(256) void upsample2d_kernel(
    const float* __restrict__ x, const float* __restrict__ filt,
    float* __restrict__ out)
{
    __shared__ float s_in[4 * WREG];      // 4 waves x 2240 B = 8960 B total

    const int tx = threadIdx.x, ty = threadIdx.y;
    const int w    = ty >> 2;             // wave id 0..3
    const int lane = (ty & 3) * 16 + tx;  // lane 0..63 within wave
    const int bc  = blockIdx.z;           // fused (batch,channel) 0..255
    const int boy = blockIdx.y, box = blockIdx.x;

    const float* xc = x + (size_t)bc * 65536;

    // ---- wave-private staging: rows [32*boy + 8*w - 3, +14), cols [32*box - 3, +38) ----
    float* sw = s_in + w * WREG;
    const int row0 = boy * 32 + w * 8 - 3;
    const int col0 = box * 32 - 3;
    #pragma unroll
    for (int k = 0; k < 9; ++k) {
        int idx = lane + k * 64;
        if (idx > 531) idx = 531;         // duplicate same-value write: benign
        int r = (idx * 1725) >> 16;       // idx / 38 (exact for idx < 608)
        int c = idx - r * 38;
        int gy = row0 + r, gx = col0 + c;
        gy = gy < 0 ? -gy : (gy > 255 ? 510 - gy : gy);
        gx = gx < 0 ? -gx : (gx > 255 ? 510 - gx : gx);
        sw[r * S + c] = xc[gy * 256 + gx];
    }
    // no barrier: each wave reads only its own slab (compiler emits lgkmcnt wait)

    // ---- 8x8 window -> registers ----
    const int xb = w * WREG + (2 * (ty & 3)) * S + 2 * tx;
    float xr[8][8];
    #pragma unroll
    for (int r = 0; r < 8; ++r) {
        #pragma unroll
        for (int cc = 0; cc < 8; ++cc)
            xr[r][cc] = s_in[xb + r * S + cc];
    }

    // ---- 576 FMAs; filter via wave-uniform scalar loads (SGPR operand) ----
    float acc[4][4] = {};
    #pragma unroll
    for (int py = 0; py < 2; ++py)
    #pragma unroll
    for (int px = 0; px < 2; ++px) {
        #pragma unroll
        for (int m = 0; m < 6; ++m)
        #pragma unroll
        for (int n = 0; n < 6; ++n) {
            const float f = filt[(11 - py - 2 * m) * 12 + (11 - px - 2 * n)];
            #pragma unroll
            for (int qy = 0; qy < 2; ++qy)
            #pragma unroll
            for (int qx = 0; qx < 2; ++qx)
                acc[2 * qy + py][2 * qx + px] =
                    fmaf(xr[qy + py + m][qx + px + n], f,
                         acc[2 * qy + py][2 * qx + px]);
        }
    }

    // ---- epilogue: x4 scale + coalesced float4 stores (no wait needed after) ----
    float* oc = out + (size_t)bc * 262144;
    const int OY0 = boy * 64 + 4 * ty;    // ty = 4*w + wy  ->  16w + 4wy
    const int OX  = box * 64 + 4 * tx;
    #pragma unroll
    for (int oy = 0; oy < 4; ++oy) {
        float4 v = make_float4(4.0f * acc[oy][0], 4.0f * acc[oy][1],
                               4.0f * acc[oy][2], 4.0f * acc[oy][3]);
        *reinterpret_cast<float4*>(&oc[(size_t)(OY0 + oy) * 512 + OX]) = v;
    }
}

extern "C" void kernel_launch(void* const* d_in, const int* in_sizes, int n_in,
                              void* d_out, int out_size, void* d_ws, size_t ws_size,
                              hipStream_t stream) {
    const float* x    = (const float*)d_in[0];   // (4,64,256,256) fp32
    const float* filt = (const float*)d_in[1];   // (12,12) fp32
    float* out = (float*)d_out;                  // (4,64,512,512) fp32

    dim3 grid(8, 8, 256);   // 8x8 tiles of 64x64; z = fused (batch,channel)
    dim3 block(16, 16, 1);
    upsample2d_kernel<<<grid, block, 0, stream>>>(x, filt, out);
}

// Round 9
// 91.934 us; speedup vs baseline: 1.6674x; 1.0011x over previous
//
#include <hip/hip_runtime.h>

// Polyphase 2x upsample, depthwise 12-tap, reflect pad, fp32.
// out[b,c,oh,ow] = 4 * sum_{m,n=0..5} x[b,c,reflect(q_y+py+m-3),reflect(q_x+px+n-3)]
//                       * filt[11-py-2m][11-px-2n],  oh=2*q_y+py, ow=2*q_x+px
//
// R7->R8: VGPR diet to get under the 64-reg cliff (8 waves/SIMD):
//  - global_load_lds staging (no dest VGPRs, no ds_write): wave-private slab
//    is linear in lane order = exactly the HW's base+lane*4 dest pattern
//  - row-streamed FMA: one 8-float LDS row live at a time instead of xr[8][8]
//  - slab padded to 576 words so chunk-8 lanes write pad, not the next slab
//  - launch_bounds(256,8) pins allocator <=64 VGPR

#define S 40             // slab row stride in words
#define WREG 576         // padded wave slab: 9 chunks x 64 words (14x40 used)

typedef __attribute__((address_space(3))) void lds_t;
typedef __attribute__((address_space(1))) const void gm_t;

__global__ __launch_bounds__(256, 8) void upsample2d_kernel(
    const float* __restrict__ x, const float* __restrict__ filt,
    float* __restrict__ out)
{
    __shared__ float s_in[4 * WREG];      // 9216 B

    const int tx = threadIdx.x, ty = threadIdx.y;
    const int w    = ty >> 2;             // wave id 0..3
    const int lane = (ty & 3) * 16 + tx;  // HW lane id within wave
    const int bc  = blockIdx.z;           // fused (batch,channel) 0..255
    const int boy = blockIdx.y, box = blockIdx.x;

    const float* xc = x + (size_t)bc * 65536;
    const int row0 = boy * 32 + w * 8 - 3;   // slab top row (pre-reflect)
    const int col0 = box * 32 - 3;           // slab left col (pre-reflect)

    float* sw = s_in + w * WREG;

    // ---- staging: 9 x global_load_lds, linear slab, reflect on source ----
    #pragma unroll
    for (int k = 0; k < 9; ++k) {
        int j = lane + 64 * k;            // slab word 0..575
        int r = (j * 1639) >> 16;         // j / 40 (exact for j < 1000)
        int c = j - r * 40;
        int gy = row0 + r, gx = col0 + c;
        gy = gy < 0 ? -gy : gy;  gy = gy > 255 ? 510 - gy : gy;
        gx = gx < 0 ? -gx : gx;  gx = gx > 255 ? 510 - gx : gx;
        __builtin_amdgcn_global_load_lds((gm_t*)(xc + gy * 256 + gx),
                                         (lds_t*)(sw + 64 * k), 4, 0, 0);
    }
    asm volatile("s_waitcnt vmcnt(0)" ::: "memory");   // wave-private: no barrier

    // ---- row-streamed compute: one slab row live at a time ----
    const int xb = w * WREG + (2 * (ty & 3)) * S + 2 * tx;
    float acc[4][4] = {};
    #pragma unroll
    for (int r = 0; r < 8; ++r) {
        float xrr[8];
        #pragma unroll
        for (int cc = 0; cc < 8; ++cc) xrr[cc] = s_in[xb + r * S + cc];
        #pragma unroll
        for (int qy = 0; qy < 2; ++qy)
        #pragma unroll
        for (int py = 0; py < 2; ++py) {
            const int m = r - qy - py;          // compile-time after unroll
            if (m >= 0 && m <= 5) {
                #pragma unroll
                for (int px = 0; px < 2; ++px)
                #pragma unroll
                for (int n = 0; n < 6; ++n) {
                    const float f = filt[(11 - py - 2 * m) * 12 + (11 - px - 2 * n)];
                    #pragma unroll
                    for (int qx = 0; qx < 2; ++qx)
                        acc[2 * qy + py][2 * qx + px] =
                            fmaf(xrr[qx + px + n], f, acc[2 * qy + py][2 * qx + px]);
                }
            }
        }
    }

    // ---- epilogue: x4 scale + coalesced float4 stores ----
    float* oc = out + (size_t)bc * 262144;
    const int OY0 = boy * 64 + 4 * ty;
    const int OX  = box * 64 + 4 * tx;
    #pragma unroll
    for (int oy = 0; oy < 4; ++oy) {
        float4 v = make_float4(4.0f * acc[oy][0], 4.0f * acc[oy][1],
                               4.0f * acc[oy][2], 4.0f * acc[oy][3]);
        *reinterpret_cast<float4*>(&oc[(size_t)(OY0 + oy) * 512 + OX]) = v;
    }
}

extern "C" void kernel_launch(void* const* d_in, const int* in_sizes, int n_in,
                              void* d_out, int out_size, void* d_ws, size_t ws_size,
                              hipStream_t stream) {
    const float* x    = (const float*)d_in[0];   // (4,64,256,256) fp32
    const float* filt = (const float*)d_in[1];   // (12,12) fp32
    float* out = (float*)d_out;                  // (4,64,512,512) fp32

    dim3 grid(8, 8, 256);   // 8x8 tiles of 64x64; z = fused (batch,channel)
    dim3 block(16, 16, 1);
    upsample2d_kernel<<<grid, block, 0, stream>>>(x, filt, out);
}